// Round 4
// baseline (1534.986 us; speedup 1.0000x reference)
//
#include <hip/hip_runtime.h>

#define IN_F 256
#define OUT_F 128
#define BSH 7
#define BNODES 128          // nodes per bucket = 1<<BSH
#define MAXBUCK 1024        // supports n_nodes <= 131072

typedef short bf16x8 __attribute__((ext_vector_type(8)));
typedef float f32x4 __attribute__((ext_vector_type(4)));

__device__ inline unsigned short f2bf(float x) {
    union { float f; unsigned u; } v; v.f = x;
    unsigned r = v.u + 0x7FFFu + ((v.u >> 16) & 1u);   // round-nearest-even
    return (unsigned short)(r >> 16);
}
__device__ inline float bf2f(unsigned short x) {
    union { unsigned u; float f; } v; v.u = ((unsigned)x) << 16;
    return v.f;
}

// ---------------------------------------------------------------------------
// zero deg[]
// ---------------------------------------------------------------------------
__global__ __launch_bounds__(256) void zero_kernel(int* __restrict__ deg, int n_nodes) {
    int i = blockIdx.x * 256 + threadIdx.x;
    if (i < n_nodes) deg[i] = 0;
}

// ---------------------------------------------------------------------------
// deg[dst[e]] += 1
// ---------------------------------------------------------------------------
__global__ __launch_bounds__(256) void deg_kernel(const int* __restrict__ dst,
                                                  int* __restrict__ deg,
                                                  int n_edges) {
    int i = blockIdx.x * 256 + threadIdx.x;
    if (i < n_edges) atomicAdd(&deg[dst[i]], 1);
}

// ---------------------------------------------------------------------------
// norm[i] = 1/sqrt(max(deg,1))
// ---------------------------------------------------------------------------
__global__ __launch_bounds__(256) void norm_kernel(const int* __restrict__ deg,
                                                   float* __restrict__ norm,
                                                   int n_nodes) {
    int i = blockIdx.x * 256 + threadIdx.x;
    if (i < n_nodes) {
        float d = (float)deg[i];
        if (d < 1.0f) d = 1.0f;
        norm[i] = 1.0f / sqrtf(d);
    }
}

// ---------------------------------------------------------------------------
// bhist[b] = sum of deg over bucket b's 128 nodes
// ---------------------------------------------------------------------------
__global__ __launch_bounds__(128) void bhist_kernel(const int* __restrict__ deg,
                                                    int* __restrict__ bhist,
                                                    int n_nodes) {
    __shared__ int ws[2];
    int i = blockIdx.x * 128 + threadIdx.x;
    int v = (i < n_nodes) ? deg[i] : 0;
    #pragma unroll
    for (int o = 32; o; o >>= 1) v += __shfl_down(v, o);
    if ((threadIdx.x & 63) == 0) ws[threadIdx.x >> 6] = v;
    __syncthreads();
    if (threadIdx.x == 0) bhist[blockIdx.x] = ws[0] + ws[1];
}

// ---------------------------------------------------------------------------
// single-block exclusive scan over nbuck bucket counts -> bstart, gcur copy
// ---------------------------------------------------------------------------
__global__ __launch_bounds__(1024) void scanb_kernel(const int* __restrict__ bhist,
                                                     int* __restrict__ bstart,
                                                     int* __restrict__ gcur,
                                                     int nbuck) {
    __shared__ int sh[1024];
    int tid = threadIdx.x;
    int v = (tid < nbuck) ? bhist[tid] : 0;
    sh[tid] = v;
    __syncthreads();
    #pragma unroll
    for (int off = 1; off < 1024; off <<= 1) {
        int t = (tid >= off) ? sh[tid - off] : 0;
        __syncthreads();
        sh[tid] += t;
        __syncthreads();
    }
    int ex = sh[tid] - v;
    if (tid < nbuck) { bstart[tid] = ex; gcur[tid] = ex; }
    if (tid == 1023) bstart[nbuck] = sh[1023];
}

// ---------------------------------------------------------------------------
// bin: two-pass LDS-histogram binning of edges into buckets.
// ebuf[pos] = (src << BSH) | (dst & 127), grouped by bucket(dst).
// ---------------------------------------------------------------------------
__global__ __launch_bounds__(256) void bin_kernel(const int* __restrict__ src,
                                                  const int* __restrict__ dst,
                                                  int* __restrict__ gcur,
                                                  unsigned* __restrict__ ebuf,
                                                  int n_edges, int nbuck) {
    __shared__ int hist[MAXBUCK];
    __shared__ int lbase[MAXBUCK];
    const int tid = threadIdx.x;
    const int chunk = (n_edges + gridDim.x - 1) / gridDim.x;
    const int lo = blockIdx.x * chunk;
    const int hi = min(lo + chunk, n_edges);

    for (int i = tid; i < nbuck; i += 256) hist[i] = 0;
    __syncthreads();
    for (int e = lo + tid; e < hi; e += 256)
        atomicAdd(&hist[dst[e] >> BSH], 1);
    __syncthreads();
    for (int i = tid; i < nbuck; i += 256) {
        int c = hist[i];
        lbase[i] = (c > 0) ? atomicAdd(&gcur[i], c) : 0;
        hist[i] = 0;            // reuse as local cursor
    }
    __syncthreads();
    for (int e = lo + tid; e < hi; e += 256) {
        int d = dst[e];
        int bkt = d >> BSH;
        int off = atomicAdd(&hist[bkt], 1);
        ebuf[lbase[bkt] + off] = ((unsigned)src[e] << BSH) | (unsigned)(d & (BNODES - 1));
    }
}

// ---------------------------------------------------------------------------
// W[256][128] f32 -> Wt[128][256] bf16
// ---------------------------------------------------------------------------
__global__ __launch_bounds__(256) void wprep_kernel(const float* __restrict__ W,
                                                    unsigned short* __restrict__ Wt) {
    int n = blockIdx.x;
    int k = threadIdx.x;
    Wt[n * IN_F + k] = f2bf(W[k * OUT_F + n]);
}

// ---------------------------------------------------------------------------
// h = bf16( feat @ W )  (UNSCALED; norm applied per-edge in agg) MFMA, LDS-free
// ---------------------------------------------------------------------------
__global__ __launch_bounds__(256) void gemm_mfma(const float* __restrict__ feat,
                                                 const unsigned short* __restrict__ Wt,
                                                 unsigned short* __restrict__ h,
                                                 int n_nodes) {
    const int wave = threadIdx.x >> 6;
    const int lane = threadIdx.x & 63;
    const int r0   = (blockIdx.x * 4 + wave) * 16;
    const int lrow = lane & 15;
    const int kgrp = (lane >> 4) * 8;

    const int row    = r0 + lrow;
    const bool rvalid = row < n_nodes;
    const int rowc   = rvalid ? row : (n_nodes - 1);
    const float nm   = rvalid ? 1.0f : 0.0f;
    const float* arow = feat + (size_t)rowc * IN_F;

    f32x4 acc[8];
    #pragma unroll
    for (int n = 0; n < 8; ++n) acc[n] = (f32x4){0.f, 0.f, 0.f, 0.f};

    #pragma unroll
    for (int k0 = 0; k0 < IN_F / 32; ++k0) {
        float4 a0 = *reinterpret_cast<const float4*>(arow + k0 * 32 + kgrp);
        float4 a1 = *reinterpret_cast<const float4*>(arow + k0 * 32 + kgrp + 4);
        bf16x8 afr;
        afr[0] = (short)f2bf(a0.x * nm);
        afr[1] = (short)f2bf(a0.y * nm);
        afr[2] = (short)f2bf(a0.z * nm);
        afr[3] = (short)f2bf(a0.w * nm);
        afr[4] = (short)f2bf(a1.x * nm);
        afr[5] = (short)f2bf(a1.y * nm);
        afr[6] = (short)f2bf(a1.z * nm);
        afr[7] = (short)f2bf(a1.w * nm);
        #pragma unroll
        for (int n = 0; n < 8; ++n) {
            bf16x8 bfr = *reinterpret_cast<const bf16x8*>(
                Wt + (size_t)(n * 16 + lrow) * IN_F + k0 * 32 + kgrp);
            acc[n] = __builtin_amdgcn_mfma_f32_16x16x32_bf16(afr, bfr, acc[n], 0, 0, 0);
        }
    }

    const int orow0 = r0 + (lane >> 4) * 4;
    #pragma unroll
    for (int n = 0; n < 8; ++n) {
        #pragma unroll
        for (int j = 0; j < 4; ++j) {
            int orow = orow0 + j;
            if (orow < n_nodes)
                h[(size_t)orow * OUT_F + n * 16 + lrow] = f2bf(acc[n][j]);
        }
    }
}

// ---------------------------------------------------------------------------
// agg: one block per bucket. LDS accum[128 nodes][128 feats] f32 (64 KB).
// Per edge: all 64 lanes of a wave gather one h row, scale by norm[src],
// LDS-atomic-add into dst-local row. Epilogue: out = accum*norm[dst]+bias.
// ---------------------------------------------------------------------------
__global__ __launch_bounds__(256) void agg_kernel(const unsigned short* __restrict__ h,
                                                  const unsigned* __restrict__ ebuf,
                                                  const int* __restrict__ bstart,
                                                  const float* __restrict__ norm,
                                                  const float* __restrict__ bias,
                                                  float* __restrict__ out,
                                                  int n_nodes) {
    __shared__ float acc[BNODES * OUT_F];   // 64 KB
    const int tid  = threadIdx.x;
    const int lane = tid & 63;
    const int wave = tid >> 6;
    const int node0 = blockIdx.x << BSH;

    #pragma unroll
    for (int i = 0; i < BNODES * OUT_F / 1024; ++i)
        *reinterpret_cast<f32x4*>(&acc[(i * 256 + tid) * 4]) = (f32x4){0.f, 0.f, 0.f, 0.f};
    __syncthreads();

    const int e0 = bstart[blockIdx.x];
    const int e1 = bstart[blockIdx.x + 1];

    for (int e = e0 + wave; e < e1; e += 4) {
        unsigned pk = ebuf[e];
        int s  = pk >> BSH;
        int dl = pk & (BNODES - 1);
        float nm = norm[s];
        const unsigned short* hr = h + (size_t)s * OUT_F;
        float v0 = bf2f(hr[lane])      * nm;
        float v1 = bf2f(hr[lane + 64]) * nm;
        atomicAdd(&acc[dl * OUT_F + lane],      v0);
        atomicAdd(&acc[dl * OUT_F + 64 + lane], v1);
    }
    __syncthreads();

    const float b0 = bias[lane];
    const float b1 = bias[lane + 64];
    for (int n = wave; n < BNODES; n += 4) {
        int g = node0 + n;
        if (g >= n_nodes) break;
        float nm = norm[g];
        out[(size_t)g * OUT_F + lane]      = acc[n * OUT_F + lane]      * nm + b0;
        out[(size_t)g * OUT_F + 64 + lane] = acc[n * OUT_F + 64 + lane] * nm + b1;
    }
}

// ---------------------------------------------------------------------------
extern "C" void kernel_launch(void* const* d_in, const int* in_sizes, int n_in,
                              void* d_out, int out_size, void* d_ws, size_t ws_size,
                              hipStream_t stream) {
    const float* feat   = (const float*)d_in[0];
    const float* weight = (const float*)d_in[1];
    const float* bias   = (const float*)d_in[2];
    const int*   src    = (const int*)d_in[3];
    const int*   dst    = (const int*)d_in[4];
    float* out = (float*)d_out;

    const int n_nodes = in_sizes[0] / IN_F;
    const int n_edges = in_sizes[3];
    const int nbuck   = (n_nodes + BNODES - 1) >> BSH;

    // ws layout (16B-aligned blocks)
    char* ws = (char*)d_ws;
    size_t off = 0;
    auto alloc = [&](size_t bytes) {
        char* p = ws + off;
        off += (bytes + 15) & ~(size_t)15;
        return p;
    };
    unsigned short* h  = (unsigned short*)alloc((size_t)n_nodes * OUT_F * 2);
    float* norm        = (float*)alloc((size_t)n_nodes * 4);
    int*   deg         = (int*)alloc((size_t)n_nodes * 4);
    int*   bhist       = (int*)alloc(MAXBUCK * 4);
    int*   bstart      = (int*)alloc((MAXBUCK + 1) * 4);
    int*   gcur        = (int*)alloc(MAXBUCK * 4);
    unsigned short* Wt = (unsigned short*)alloc((size_t)OUT_F * IN_F * 2);
    unsigned* ebuf     = (unsigned*)alloc((size_t)n_edges * 4);

    zero_kernel<<<(n_nodes + 255) / 256, 256, 0, stream>>>(deg, n_nodes);
    deg_kernel<<<(n_edges + 255) / 256, 256, 0, stream>>>(dst, deg, n_edges);
    norm_kernel<<<(n_nodes + 255) / 256, 256, 0, stream>>>(deg, norm, n_nodes);
    bhist_kernel<<<nbuck, 128, 0, stream>>>(deg, bhist, n_nodes);
    scanb_kernel<<<1, 1024, 0, stream>>>(bhist, bstart, gcur, nbuck);
    bin_kernel<<<128, 256, 0, stream>>>(src, dst, gcur, ebuf, n_edges, nbuck);
    wprep_kernel<<<OUT_F, IN_F, 0, stream>>>(weight, Wt);
    gemm_mfma<<<(n_nodes + 63) / 64, 256, 0, stream>>>(feat, Wt, h, n_nodes);
    agg_kernel<<<nbuck, 256, 0, stream>>>(h, ebuf, bstart, norm, bias, out, n_nodes);
}

// Round 5
// 309.737 us; speedup vs baseline: 4.9558x; 4.9558x over previous
//
#include <hip/hip_runtime.h>

#define IN_F 256
#define OUT_F 128
#define BSH 7
#define BNODES 128          // nodes per bucket = 1<<BSH
#define MAXBUCK 1024        // supports n_nodes <= 131072

typedef short bf16x8 __attribute__((ext_vector_type(8)));
typedef float f32x4 __attribute__((ext_vector_type(4)));

__device__ inline unsigned short f2bf(float x) {
    union { float f; unsigned u; } v; v.f = x;
    unsigned r = v.u + 0x7FFFu + ((v.u >> 16) & 1u);   // round-nearest-even
    return (unsigned short)(r >> 16);
}
__device__ inline float bf2f(unsigned short x) {
    union { unsigned u; float f; } v; v.u = ((unsigned)x) << 16;
    return v.f;
}

// ---------------------------------------------------------------------------
__global__ __launch_bounds__(256) void zero_kernel(int* __restrict__ deg, int n_nodes) {
    int i = blockIdx.x * 256 + threadIdx.x;
    if (i < n_nodes) deg[i] = 0;
}

__global__ __launch_bounds__(256) void deg_kernel(const int* __restrict__ dst,
                                                  int* __restrict__ deg,
                                                  int n_edges) {
    int i = blockIdx.x * 256 + threadIdx.x;
    if (i < n_edges) atomicAdd(&deg[dst[i]], 1);
}

__global__ __launch_bounds__(256) void norm_kernel(const int* __restrict__ deg,
                                                   float* __restrict__ norm,
                                                   int n_nodes) {
    int i = blockIdx.x * 256 + threadIdx.x;
    if (i < n_nodes) {
        float d = (float)deg[i];
        if (d < 1.0f) d = 1.0f;
        norm[i] = 1.0f / sqrtf(d);
    }
}

// ---------------------------------------------------------------------------
// Node-level exclusive scan of deg -> rstart (3 kernels, 1024 elems/block)
// ---------------------------------------------------------------------------
__global__ __launch_bounds__(256) void scan1_kernel(const int* __restrict__ deg,
                                                    int* __restrict__ rstart,
                                                    int* __restrict__ bsum,
                                                    int n) {
    __shared__ int sh[256];
    const int tid = threadIdx.x;
    const int base = blockIdx.x * 1024;
    int v[4], s = 0;
    #pragma unroll
    for (int j = 0; j < 4; ++j) {
        int idx = base + tid * 4 + j;
        v[j] = (idx < n) ? deg[idx] : 0;
        s += v[j];
    }
    sh[tid] = s;
    __syncthreads();
    #pragma unroll
    for (int off = 1; off < 256; off <<= 1) {
        int t = (tid >= off) ? sh[tid - off] : 0;
        __syncthreads();
        sh[tid] += t;
        __syncthreads();
    }
    int ex = sh[tid] - s;
    #pragma unroll
    for (int j = 0; j < 4; ++j) {
        int idx = base + tid * 4 + j;
        if (idx < n) rstart[idx] = ex;
        ex += v[j];
    }
    if (tid == 255) bsum[blockIdx.x] = sh[255];
}

__global__ __launch_bounds__(256) void scan2_kernel(int* __restrict__ bsum, int nb) {
    __shared__ int sh[256];
    const int tid = threadIdx.x;
    int v[4], s = 0;
    #pragma unroll
    for (int j = 0; j < 4; ++j) {
        int idx = tid * 4 + j;
        v[j] = (idx < nb) ? bsum[idx] : 0;
        s += v[j];
    }
    sh[tid] = s;
    __syncthreads();
    #pragma unroll
    for (int off = 1; off < 256; off <<= 1) {
        int t = (tid >= off) ? sh[tid - off] : 0;
        __syncthreads();
        sh[tid] += t;
        __syncthreads();
    }
    int ex = sh[tid] - s;
    #pragma unroll
    for (int j = 0; j < 4; ++j) {
        int idx = tid * 4 + j;
        if (idx < nb) { int old = v[j]; bsum[idx] = ex; ex += old; }
    }
}

__global__ __launch_bounds__(256) void scan3_kernel(int* __restrict__ rstart,
                                                    const int* __restrict__ bsum,
                                                    int n) {
    int i = blockIdx.x * 256 + threadIdx.x;
    if (i < n) rstart[i] += bsum[i >> 10];
}

// ---------------------------------------------------------------------------
// bhist[b] = bucket edge count (sum of deg over its 128 nodes)
// ---------------------------------------------------------------------------
__global__ __launch_bounds__(128) void bhist_kernel(const int* __restrict__ deg,
                                                    int* __restrict__ bhist,
                                                    int n_nodes) {
    __shared__ int ws[2];
    int i = blockIdx.x * 128 + threadIdx.x;
    int v = (i < n_nodes) ? deg[i] : 0;
    #pragma unroll
    for (int o = 32; o; o >>= 1) v += __shfl_down(v, o);
    if ((threadIdx.x & 63) == 0) ws[threadIdx.x >> 6] = v;
    __syncthreads();
    if (threadIdx.x == 0) bhist[blockIdx.x] = ws[0] + ws[1];
}

// single-block exclusive scan over bucket counts -> bstart, gcur
__global__ __launch_bounds__(1024) void scanb_kernel(const int* __restrict__ bhist,
                                                     int* __restrict__ bstart,
                                                     int* __restrict__ gcur,
                                                     int nbuck) {
    __shared__ int sh[1024];
    int tid = threadIdx.x;
    int v = (tid < nbuck) ? bhist[tid] : 0;
    sh[tid] = v;
    __syncthreads();
    #pragma unroll
    for (int off = 1; off < 1024; off <<= 1) {
        int t = (tid >= off) ? sh[tid - off] : 0;
        __syncthreads();
        sh[tid] += t;
        __syncthreads();
    }
    int ex = sh[tid] - v;
    if (tid < nbuck) { bstart[tid] = ex; gcur[tid] = ex; }
    if (tid == 1023) bstart[nbuck] = sh[1023];
}

// ---------------------------------------------------------------------------
// bin1: two-pass LDS-histogram binning of edges into bucket-grouped ebuf.
// ebuf[pos] = (src << BSH) | (dst & 127)
// ---------------------------------------------------------------------------
__global__ __launch_bounds__(256) void bin1_kernel(const int* __restrict__ src,
                                                   const int* __restrict__ dst,
                                                   int* __restrict__ gcur,
                                                   unsigned* __restrict__ ebuf,
                                                   int n_edges, int nbuck) {
    __shared__ int hist[MAXBUCK];
    __shared__ int lbase[MAXBUCK];
    const int tid = threadIdx.x;
    const int chunk = (n_edges + gridDim.x - 1) / gridDim.x;
    const int lo = blockIdx.x * chunk;
    const int hi = min(lo + chunk, n_edges);

    for (int i = tid; i < nbuck; i += 256) hist[i] = 0;
    __syncthreads();
    for (int e = lo + tid; e < hi; e += 256)
        atomicAdd(&hist[dst[e] >> BSH], 1);
    __syncthreads();
    for (int i = tid; i < nbuck; i += 256) {
        int c = hist[i];
        lbase[i] = (c > 0) ? atomicAdd(&gcur[i], c) : 0;
        hist[i] = 0;            // reuse as local cursor
    }
    __syncthreads();
    for (int e = lo + tid; e < hi; e += 256) {
        int d = dst[e];
        int bkt = d >> BSH;
        int off = atomicAdd(&hist[bkt], 1);
        ebuf[lbase[bkt] + off] = ((unsigned)src[e] << BSH) | (unsigned)(d & (BNODES - 1));
    }
}

// ---------------------------------------------------------------------------
// bin2: one block per bucket — scatter bucket's edges into exact per-node CSR.
// Writes stay inside the bucket's own eidx window (~8 KB) -> L2-local.
// ---------------------------------------------------------------------------
__global__ __launch_bounds__(256) void bin2_kernel(const unsigned* __restrict__ ebuf,
                                                   const int* __restrict__ bstart,
                                                   const int* __restrict__ rstart,
                                                   int* __restrict__ eidx,
                                                   int n_nodes) {
    __shared__ int lcur[BNODES];
    __shared__ int rs[BNODES];
    const int tid = threadIdx.x;
    const int node0 = blockIdx.x << BSH;

    if (tid < BNODES) {
        lcur[tid] = 0;
        int g = node0 + tid;
        rs[tid] = (g < n_nodes) ? rstart[g] : 0;
    }
    __syncthreads();

    const int e0 = bstart[blockIdx.x];
    const int e1 = bstart[blockIdx.x + 1];
    for (int e = e0 + tid; e < e1; e += 256) {
        unsigned pk = ebuf[e];
        int dl = pk & (BNODES - 1);
        int pos = atomicAdd(&lcur[dl], 1);
        eidx[rs[dl] + pos] = (int)(pk >> BSH);
    }
}

// ---------------------------------------------------------------------------
// W[256][128] f32 -> Wt[128][256] bf16
// ---------------------------------------------------------------------------
__global__ __launch_bounds__(256) void wprep_kernel(const float* __restrict__ W,
                                                    unsigned short* __restrict__ Wt) {
    int n = blockIdx.x;
    int k = threadIdx.x;
    Wt[n * IN_F + k] = f2bf(W[k * OUT_F + n]);
}

// ---------------------------------------------------------------------------
// h = bf16( (feat * norm[row]) @ W )  MFMA 16x16x32 bf16, LDS-free
// ---------------------------------------------------------------------------
__global__ __launch_bounds__(256) void gemm_mfma(const float* __restrict__ feat,
                                                 const unsigned short* __restrict__ Wt,
                                                 const float* __restrict__ norm,
                                                 unsigned short* __restrict__ h,
                                                 int n_nodes) {
    const int wave = threadIdx.x >> 6;
    const int lane = threadIdx.x & 63;
    const int r0   = (blockIdx.x * 4 + wave) * 16;
    const int lrow = lane & 15;
    const int kgrp = (lane >> 4) * 8;

    const int row    = r0 + lrow;
    const bool rvalid = row < n_nodes;
    const int rowc   = rvalid ? row : (n_nodes - 1);
    const float nm   = rvalid ? norm[rowc] : 0.0f;
    const float* arow = feat + (size_t)rowc * IN_F;

    f32x4 acc[8];
    #pragma unroll
    for (int n = 0; n < 8; ++n) acc[n] = (f32x4){0.f, 0.f, 0.f, 0.f};

    #pragma unroll
    for (int k0 = 0; k0 < IN_F / 32; ++k0) {
        float4 a0 = *reinterpret_cast<const float4*>(arow + k0 * 32 + kgrp);
        float4 a1 = *reinterpret_cast<const float4*>(arow + k0 * 32 + kgrp + 4);
        bf16x8 afr;
        afr[0] = (short)f2bf(a0.x * nm);
        afr[1] = (short)f2bf(a0.y * nm);
        afr[2] = (short)f2bf(a0.z * nm);
        afr[3] = (short)f2bf(a0.w * nm);
        afr[4] = (short)f2bf(a1.x * nm);
        afr[5] = (short)f2bf(a1.y * nm);
        afr[6] = (short)f2bf(a1.z * nm);
        afr[7] = (short)f2bf(a1.w * nm);
        #pragma unroll
        for (int n = 0; n < 8; ++n) {
            bf16x8 bfr = *reinterpret_cast<const bf16x8*>(
                Wt + (size_t)(n * 16 + lrow) * IN_F + k0 * 32 + kgrp);
            acc[n] = __builtin_amdgcn_mfma_f32_16x16x32_bf16(afr, bfr, acc[n], 0, 0, 0);
        }
    }

    const int orow0 = r0 + (lane >> 4) * 4;
    #pragma unroll
    for (int n = 0; n < 8; ++n) {
        #pragma unroll
        for (int j = 0; j < 4; ++j) {
            int orow = orow0 + j;
            if (orow < n_nodes)
                h[(size_t)orow * OUT_F + n * 16 + lrow] = f2bf(acc[n][j]);
        }
    }
}

// ---------------------------------------------------------------------------
// agg: one wave per dst node (round-2 structure). 64-lane coalesced 256 B
// h-row gathers, register accumulation, single write per output row.
// ---------------------------------------------------------------------------
__global__ __launch_bounds__(256) void agg_kernel(const unsigned short* __restrict__ h,
                                                  const int* __restrict__ eidx,
                                                  const int* __restrict__ rstart,
                                                  const int* __restrict__ deg,
                                                  const float* __restrict__ norm,
                                                  const float* __restrict__ bias,
                                                  float* __restrict__ out,
                                                  int n_nodes) {
    const int wave = threadIdx.x >> 6;
    const int lane = threadIdx.x & 63;
    const int node = blockIdx.x * 4 + wave;
    if (node >= n_nodes) return;

    const int start = rstart[node];
    const int cnt   = deg[node];

    float a0 = 0.f, a1 = 0.f;
    int i = 0;
    for (; i + 2 <= cnt; i += 2) {
        int s0 = eidx[start + i];
        int s1 = eidx[start + i + 1];
        unsigned v0 = *reinterpret_cast<const unsigned*>(h + (size_t)s0 * OUT_F + lane * 2);
        unsigned v1 = *reinterpret_cast<const unsigned*>(h + (size_t)s1 * OUT_F + lane * 2);
        a0 += bf2f((unsigned short)(v0 & 0xffffu)) + bf2f((unsigned short)(v1 & 0xffffu));
        a1 += bf2f((unsigned short)(v0 >> 16))     + bf2f((unsigned short)(v1 >> 16));
    }
    if (i < cnt) {
        int s0 = eidx[start + i];
        unsigned v0 = *reinterpret_cast<const unsigned*>(h + (size_t)s0 * OUT_F + lane * 2);
        a0 += bf2f((unsigned short)(v0 & 0xffffu));
        a1 += bf2f((unsigned short)(v0 >> 16));
    }

    const float nm = norm[node];
    float2 r;
    r.x = a0 * nm + bias[lane * 2];
    r.y = a1 * nm + bias[lane * 2 + 1];
    *reinterpret_cast<float2*>(out + (size_t)node * OUT_F + lane * 2) = r;
}

// ---------------------------------------------------------------------------
extern "C" void kernel_launch(void* const* d_in, const int* in_sizes, int n_in,
                              void* d_out, int out_size, void* d_ws, size_t ws_size,
                              hipStream_t stream) {
    const float* feat   = (const float*)d_in[0];
    const float* weight = (const float*)d_in[1];
    const float* bias   = (const float*)d_in[2];
    const int*   src    = (const int*)d_in[3];
    const int*   dst    = (const int*)d_in[4];
    float* out = (float*)d_out;

    const int n_nodes = in_sizes[0] / IN_F;
    const int n_edges = in_sizes[3];
    const int nbuck   = (n_nodes + BNODES - 1) >> BSH;
    const int nb      = (n_nodes + 1023) / 1024;

    // ws layout (16B-aligned)
    char* ws = (char*)d_ws;
    size_t off = 0;
    auto alloc = [&](size_t bytes) {
        char* p = ws + off;
        off += (bytes + 15) & ~(size_t)15;
        return p;
    };
    unsigned short* h  = (unsigned short*)alloc((size_t)n_nodes * OUT_F * 2);
    float* norm        = (float*)alloc((size_t)n_nodes * 4);
    int*   deg         = (int*)alloc((size_t)n_nodes * 4);
    int*   rstart      = (int*)alloc((size_t)n_nodes * 4);
    int*   bsum        = (int*)alloc(1024 * 4);
    int*   bhist       = (int*)alloc(MAXBUCK * 4);
    int*   bstart      = (int*)alloc((MAXBUCK + 1) * 4);
    int*   gcur        = (int*)alloc(MAXBUCK * 4);
    unsigned short* Wt = (unsigned short*)alloc((size_t)OUT_F * IN_F * 2);
    unsigned* ebuf     = (unsigned*)alloc((size_t)n_edges * 4);
    int*   eidx        = (int*)alloc((size_t)n_edges * 4);

    zero_kernel<<<(n_nodes + 255) / 256, 256, 0, stream>>>(deg, n_nodes);
    deg_kernel<<<(n_edges + 255) / 256, 256, 0, stream>>>(dst, deg, n_edges);
    norm_kernel<<<(n_nodes + 255) / 256, 256, 0, stream>>>(deg, norm, n_nodes);
    // node-level CSR offsets
    scan1_kernel<<<nb, 256, 0, stream>>>(deg, rstart, bsum, n_nodes);
    scan2_kernel<<<1, 256, 0, stream>>>(bsum, nb);
    scan3_kernel<<<(n_nodes + 255) / 256, 256, 0, stream>>>(rstart, bsum, n_nodes);
    // bucket-level offsets
    bhist_kernel<<<nbuck, 128, 0, stream>>>(deg, bhist, n_nodes);
    scanb_kernel<<<1, 1024, 0, stream>>>(bhist, bstart, gcur, nbuck);
    // two-phase binning -> exact CSR
    bin1_kernel<<<128, 256, 0, stream>>>(src, dst, gcur, ebuf, n_edges, nbuck);
    bin2_kernel<<<nbuck, 256, 0, stream>>>(ebuf, bstart, rstart, eidx, n_nodes);
    // dense compute
    wprep_kernel<<<OUT_F, IN_F, 0, stream>>>(weight, Wt);
    gemm_mfma<<<(n_nodes + 63) / 64, 256, 0, stream>>>(feat, Wt, norm, h, n_nodes);
    agg_kernel<<<(n_nodes + 3) / 4, 256, 0, stream>>>(h, eidx, rstart, deg, norm, bias, out, n_nodes);
}

// Round 6
// 208.885 us; speedup vs baseline: 7.3485x; 1.4828x over previous
//
#include <hip/hip_runtime.h>

#define IN_F 256
#define OUT_F 128
#define BSH 7
#define BNODES 128          // nodes per bucket = 1<<BSH
#define MAXBUCK 1024        // supports n_nodes <= 131072
#define BIN_BLOCKS 256

typedef short bf16x8 __attribute__((ext_vector_type(8)));
typedef float f32x4 __attribute__((ext_vector_type(4)));

__device__ inline unsigned short f2bf(float x) {
    union { float f; unsigned u; } v; v.f = x;
    unsigned r = v.u + 0x7FFFu + ((v.u >> 16) & 1u);   // round-nearest-even
    return (unsigned short)(r >> 16);
}
__device__ inline float bf2f(unsigned short x) {
    union { unsigned u; float f; } v; v.u = ((unsigned)x) << 16;
    return v.f;
}

// ---------------------------------------------------------------------------
// wprep: Wt[128][256] = bf16(W^T). Also zeroes bhist (128 blocks x 8 = 1024).
// Launched FIRST; stream order guarantees bhist=0 before bin1a.
// ---------------------------------------------------------------------------
__global__ __launch_bounds__(256) void wprep_kernel(const float* __restrict__ W,
                                                    unsigned short* __restrict__ Wt,
                                                    int* __restrict__ bhist) {
    int n = blockIdx.x;      // 0..127
    int k = threadIdx.x;     // 0..255
    Wt[n * IN_F + k] = f2bf(W[k * OUT_F + n]);
    if (threadIdx.x < 8) bhist[blockIdx.x * 8 + threadIdx.x] = 0;
}

// ---------------------------------------------------------------------------
// bin1a: per-block LDS histogram of dst buckets -> global bhist accumulate.
// Replaces the per-node deg_kernel (1.6M atomics on 400KB -> ~100K atomics
// on 3KB, line-grouped).
// ---------------------------------------------------------------------------
__global__ __launch_bounds__(256) void bin1a_kernel(const int* __restrict__ dst,
                                                    int* __restrict__ bhist,
                                                    int n_edges, int nbuck) {
    __shared__ int hist[MAXBUCK];
    const int tid = threadIdx.x;
    const int chunk = (n_edges + gridDim.x - 1) / gridDim.x;
    const int lo = blockIdx.x * chunk;
    const int hi = min(lo + chunk, n_edges);

    for (int i = tid; i < MAXBUCK; i += 256) hist[i] = 0;
    __syncthreads();
    for (int e = lo + tid; e < hi; e += 256)
        atomicAdd(&hist[dst[e] >> BSH], 1);
    __syncthreads();
    for (int i = tid; i < nbuck; i += 256) {
        int c = hist[i];
        if (c) atomicAdd(&bhist[i], c);
    }
}

// ---------------------------------------------------------------------------
// scanb: single-block exclusive scan over bucket counts -> bstart, gcur.
// Also writes the CSR sentinel rstart[n_nodes] = n_edges.
// ---------------------------------------------------------------------------
__global__ __launch_bounds__(1024) void scanb_kernel(const int* __restrict__ bhist,
                                                     int* __restrict__ bstart,
                                                     int* __restrict__ gcur,
                                                     int* __restrict__ rstart,
                                                     int nbuck, int n_nodes) {
    __shared__ int sh[1024];
    int tid = threadIdx.x;
    int v = (tid < nbuck) ? bhist[tid] : 0;
    sh[tid] = v;
    __syncthreads();
    #pragma unroll
    for (int off = 1; off < 1024; off <<= 1) {
        int t = (tid >= off) ? sh[tid - off] : 0;
        __syncthreads();
        sh[tid] += t;
        __syncthreads();
    }
    int ex = sh[tid] - v;
    if (tid < nbuck) { bstart[tid] = ex; gcur[tid] = ex; }
    if (tid == 1023) {
        bstart[nbuck] = sh[1023];
        rstart[n_nodes] = sh[1023];   // sentinel (== n_edges)
    }
}

// ---------------------------------------------------------------------------
// bin1b: two-pass LDS-histogram binning into bucket-grouped ebuf.
// ebuf[pos] = (src << BSH) | (dst & 127)
// ---------------------------------------------------------------------------
__global__ __launch_bounds__(256) void bin1b_kernel(const int* __restrict__ src,
                                                    const int* __restrict__ dst,
                                                    int* __restrict__ gcur,
                                                    unsigned* __restrict__ ebuf,
                                                    int n_edges, int nbuck) {
    __shared__ int hist[MAXBUCK];
    __shared__ int lbase[MAXBUCK];
    const int tid = threadIdx.x;
    const int chunk = (n_edges + gridDim.x - 1) / gridDim.x;
    const int lo = blockIdx.x * chunk;
    const int hi = min(lo + chunk, n_edges);

    for (int i = tid; i < nbuck; i += 256) hist[i] = 0;
    __syncthreads();
    for (int e = lo + tid; e < hi; e += 256)
        atomicAdd(&hist[dst[e] >> BSH], 1);
    __syncthreads();
    for (int i = tid; i < nbuck; i += 256) {
        int c = hist[i];
        lbase[i] = (c > 0) ? atomicAdd(&gcur[i], c) : 0;
        hist[i] = 0;            // reuse as local cursor
    }
    __syncthreads();
    for (int e = lo + tid; e < hi; e += 256) {
        int d = dst[e];
        int bkt = d >> BSH;
        int off = atomicAdd(&hist[bkt], 1);
        ebuf[lbase[bkt] + off] = ((unsigned)src[e] << BSH) | (unsigned)(d & (BNODES - 1));
    }
}

// ---------------------------------------------------------------------------
// bin2: one block per bucket. Derives per-node counts from ebuf (LDS),
// scans them (LDS, 128-wide) -> rstart + norm, then places edges into the
// exact per-node CSR eidx. All writes bucket-local.
// ---------------------------------------------------------------------------
__global__ __launch_bounds__(256) void bin2_kernel(const unsigned* __restrict__ ebuf,
                                                   const int* __restrict__ bstart,
                                                   int* __restrict__ rstart,
                                                   float* __restrict__ norm,
                                                   int* __restrict__ eidx,
                                                   int n_nodes) {
    __shared__ int lcnt[BNODES];
    __shared__ int lex[BNODES];
    const int tid = threadIdx.x;
    const int node0 = blockIdx.x << BSH;
    const int e0 = bstart[blockIdx.x];
    const int e1 = bstart[blockIdx.x + 1];

    if (tid < BNODES) lcnt[tid] = 0;
    __syncthreads();
    for (int e = e0 + tid; e < e1; e += 256)
        atomicAdd(&lcnt[ebuf[e] & (BNODES - 1)], 1);
    __syncthreads();

    // 128-wide Hillis-Steele inclusive scan in lex
    int own = (tid < BNODES) ? lcnt[tid] : 0;
    if (tid < BNODES) lex[tid] = own;
    __syncthreads();
    #pragma unroll
    for (int off = 1; off < BNODES; off <<= 1) {
        int t = (tid >= off && tid < BNODES) ? lex[tid - off] : 0;
        __syncthreads();
        if (tid < BNODES) lex[tid] += t;
        __syncthreads();
    }
    if (tid < BNODES) {
        int ex = lex[tid] - own;       // exclusive
        lex[tid] = ex;
        int g = node0 + tid;
        if (g <= n_nodes) rstart[g] = e0 + ex;   // g==n_nodes: sentinel (consistent)
        if (g < n_nodes) {
            float d = (float)own;
            if (d < 1.0f) d = 1.0f;
            norm[g] = 1.0f / sqrtf(d);
        }
        lcnt[tid] = 0;                 // reuse as cursor
    }
    __syncthreads();

    for (int e = e0 + tid; e < e1; e += 256) {
        unsigned pk = ebuf[e];
        int dl = pk & (BNODES - 1);
        int pos = atomicAdd(&lcnt[dl], 1);
        eidx[e0 + lex[dl] + pos] = (int)(pk >> BSH);
    }
}

// ---------------------------------------------------------------------------
// gemm: h = bf16( feat @ W )   (UNSCALED; norm applied per-edge in agg)
// MFMA 16x16x32 bf16, LDS-free. Rows >= n_nodes produce garbage h but are
// never referenced (eidx in [0, n_nodes)); writes are guarded.
// ---------------------------------------------------------------------------
__global__ __launch_bounds__(256) void gemm_mfma(const float* __restrict__ feat,
                                                 const unsigned short* __restrict__ Wt,
                                                 unsigned short* __restrict__ h,
                                                 int n_nodes) {
    const int wave = threadIdx.x >> 6;
    const int lane = threadIdx.x & 63;
    const int r0   = (blockIdx.x * 4 + wave) * 16;
    const int lrow = lane & 15;
    const int kgrp = (lane >> 4) * 8;

    const int row  = r0 + lrow;
    const int rowc = (row < n_nodes) ? row : (n_nodes - 1);
    const float* arow = feat + (size_t)rowc * IN_F;

    f32x4 acc[8];
    #pragma unroll
    for (int n = 0; n < 8; ++n) acc[n] = (f32x4){0.f, 0.f, 0.f, 0.f};

    #pragma unroll
    for (int k0 = 0; k0 < IN_F / 32; ++k0) {
        float4 a0 = *reinterpret_cast<const float4*>(arow + k0 * 32 + kgrp);
        float4 a1 = *reinterpret_cast<const float4*>(arow + k0 * 32 + kgrp + 4);
        bf16x8 afr;
        afr[0] = (short)f2bf(a0.x);
        afr[1] = (short)f2bf(a0.y);
        afr[2] = (short)f2bf(a0.z);
        afr[3] = (short)f2bf(a0.w);
        afr[4] = (short)f2bf(a1.x);
        afr[5] = (short)f2bf(a1.y);
        afr[6] = (short)f2bf(a1.z);
        afr[7] = (short)f2bf(a1.w);
        #pragma unroll
        for (int n = 0; n < 8; ++n) {
            bf16x8 bfr = *reinterpret_cast<const bf16x8*>(
                Wt + (size_t)(n * 16 + lrow) * IN_F + k0 * 32 + kgrp);
            acc[n] = __builtin_amdgcn_mfma_f32_16x16x32_bf16(afr, bfr, acc[n], 0, 0, 0);
        }
    }

    const int orow0 = r0 + (lane >> 4) * 4;
    #pragma unroll
    for (int n = 0; n < 8; ++n) {
        #pragma unroll
        for (int j = 0; j < 4; ++j) {
            int orow = orow0 + j;
            if (orow < n_nodes)
                h[(size_t)orow * OUT_F + n * 16 + lrow] = f2bf(acc[n][j]);
        }
    }
}

// ---------------------------------------------------------------------------
// agg: one wave per dst node. 4-deep unrolled gather of h rows (64 lanes x
// 4 B coalesced), per-edge norm[src] scale, register accumulate, one write.
// ---------------------------------------------------------------------------
__global__ __launch_bounds__(256) void agg_kernel(const unsigned short* __restrict__ h,
                                                  const int* __restrict__ eidx,
                                                  const int* __restrict__ rstart,
                                                  const float* __restrict__ norm,
                                                  const float* __restrict__ bias,
                                                  float* __restrict__ out,
                                                  int n_nodes) {
    const int wave = threadIdx.x >> 6;
    const int lane = threadIdx.x & 63;
    const int node = blockIdx.x * 4 + wave;
    if (node >= n_nodes) return;

    const int start = rstart[node];
    const int cnt   = rstart[node + 1] - start;

    float a0 = 0.f, a1 = 0.f;
    int i = 0;
    for (; i + 4 <= cnt; i += 4) {
        int s0 = eidx[start + i];
        int s1 = eidx[start + i + 1];
        int s2 = eidx[start + i + 2];
        int s3 = eidx[start + i + 3];
        float n0 = norm[s0], n1 = norm[s1], n2 = norm[s2], n3 = norm[s3];
        unsigned v0 = *reinterpret_cast<const unsigned*>(h + (size_t)s0 * OUT_F + lane * 2);
        unsigned v1 = *reinterpret_cast<const unsigned*>(h + (size_t)s1 * OUT_F + lane * 2);
        unsigned v2 = *reinterpret_cast<const unsigned*>(h + (size_t)s2 * OUT_F + lane * 2);
        unsigned v3 = *reinterpret_cast<const unsigned*>(h + (size_t)s3 * OUT_F + lane * 2);
        a0 += bf2f((unsigned short)(v0 & 0xffffu)) * n0;
        a1 += bf2f((unsigned short)(v0 >> 16))     * n0;
        a0 += bf2f((unsigned short)(v1 & 0xffffu)) * n1;
        a1 += bf2f((unsigned short)(v1 >> 16))     * n1;
        a0 += bf2f((unsigned short)(v2 & 0xffffu)) * n2;
        a1 += bf2f((unsigned short)(v2 >> 16))     * n2;
        a0 += bf2f((unsigned short)(v3 & 0xffffu)) * n3;
        a1 += bf2f((unsigned short)(v3 >> 16))     * n3;
    }
    for (; i < cnt; ++i) {
        int s = eidx[start + i];
        float nm = norm[s];
        unsigned v = *reinterpret_cast<const unsigned*>(h + (size_t)s * OUT_F + lane * 2);
        a0 += bf2f((unsigned short)(v & 0xffffu)) * nm;
        a1 += bf2f((unsigned short)(v >> 16))     * nm;
    }

    const float nd = norm[node];
    float2 r;
    r.x = a0 * nd + bias[lane * 2];
    r.y = a1 * nd + bias[lane * 2 + 1];
    *reinterpret_cast<float2*>(out + (size_t)node * OUT_F + lane * 2) = r;
}

// ---------------------------------------------------------------------------
extern "C" void kernel_launch(void* const* d_in, const int* in_sizes, int n_in,
                              void* d_out, int out_size, void* d_ws, size_t ws_size,
                              hipStream_t stream) {
    const float* feat   = (const float*)d_in[0];
    const float* weight = (const float*)d_in[1];
    const float* bias   = (const float*)d_in[2];
    const int*   src    = (const int*)d_in[3];
    const int*   dst    = (const int*)d_in[4];
    float* out = (float*)d_out;

    const int n_nodes = in_sizes[0] / IN_F;
    const int n_edges = in_sizes[3];
    const int nbuck   = (n_nodes + BNODES - 1) >> BSH;

    // ws layout (16B-aligned)
    char* ws = (char*)d_ws;
    size_t off = 0;
    auto alloc = [&](size_t bytes) {
        char* p = ws + off;
        off += (bytes + 15) & ~(size_t)15;
        return p;
    };
    unsigned short* h  = (unsigned short*)alloc((size_t)n_nodes * OUT_F * 2);
    float* norm        = (float*)alloc((size_t)n_nodes * 4);
    int*   rstart      = (int*)alloc(((size_t)n_nodes + 1) * 4);
    int*   bhist       = (int*)alloc(MAXBUCK * 4);
    int*   bstart      = (int*)alloc((MAXBUCK + 1) * 4);
    int*   gcur        = (int*)alloc(MAXBUCK * 4);
    unsigned short* Wt = (unsigned short*)alloc((size_t)OUT_F * IN_F * 2);
    unsigned* ebuf     = (unsigned*)alloc((size_t)n_edges * 4);
    int*   eidx        = (int*)alloc((size_t)n_edges * 4);

    wprep_kernel<<<OUT_F, IN_F, 0, stream>>>(weight, Wt, bhist);          // + bhist=0
    bin1a_kernel<<<BIN_BLOCKS, 256, 0, stream>>>(dst, bhist, n_edges, nbuck);
    scanb_kernel<<<1, 1024, 0, stream>>>(bhist, bstart, gcur, rstart, nbuck, n_nodes);
    bin1b_kernel<<<BIN_BLOCKS, 256, 0, stream>>>(src, dst, gcur, ebuf, n_edges, nbuck);
    gemm_mfma<<<(n_nodes + 63) / 64, 256, 0, stream>>>(feat, Wt, h, n_nodes);
    bin2_kernel<<<nbuck, 256, 0, stream>>>(ebuf, bstart, rstart, norm, eidx, n_nodes);
    agg_kernel<<<(n_nodes + 3) / 4, 256, 0, stream>>>(h, eidx, rstart, norm, bias, out, n_nodes);
}

// Round 7
// 199.680 us; speedup vs baseline: 7.6872x; 1.0461x over previous
//
#include <hip/hip_runtime.h>

#define IN_F 256
#define OUT_F 128
#define BSH 7
#define BNODES 128          // nodes per bucket = 1<<BSH
#define MAXBUCK 1024        // supports n_nodes <= 131072
#define BIN_BLOCKS 256

typedef short bf16x8 __attribute__((ext_vector_type(8)));
typedef float f32x4 __attribute__((ext_vector_type(4)));

__device__ inline unsigned short f2bf(float x) {
    union { float f; unsigned u; } v; v.f = x;
    unsigned r = v.u + 0x7FFFu + ((v.u >> 16) & 1u);   // round-nearest-even
    return (unsigned short)(r >> 16);
}
__device__ inline float bf2f(unsigned short x) {
    union { unsigned u; float f; } v; v.u = ((unsigned)x) << 16;
    return v.f;
}

// ---------------------------------------------------------------------------
// wprep: Wt[128][256] = bf16(W^T). Also zeroes bhist.
// ---------------------------------------------------------------------------
__global__ __launch_bounds__(256) void wprep_kernel(const float* __restrict__ W,
                                                    unsigned short* __restrict__ Wt,
                                                    int* __restrict__ bhist) {
    int n = blockIdx.x;      // 0..127
    int k = threadIdx.x;     // 0..255
    Wt[n * IN_F + k] = f2bf(W[k * OUT_F + n]);
    if (threadIdx.x < 8) bhist[blockIdx.x * 8 + threadIdx.x] = 0;
}

// ---------------------------------------------------------------------------
// bin1a: per-block LDS histogram of dst buckets -> global bhist accumulate.
// ---------------------------------------------------------------------------
__global__ __launch_bounds__(256) void bin1a_kernel(const int* __restrict__ dst,
                                                    int* __restrict__ bhist,
                                                    int n_edges, int nbuck) {
    __shared__ int hist[MAXBUCK];
    const int tid = threadIdx.x;
    const int chunk = (n_edges + gridDim.x - 1) / gridDim.x;
    const int lo = blockIdx.x * chunk;
    const int hi = min(lo + chunk, n_edges);

    for (int i = tid; i < MAXBUCK; i += 256) hist[i] = 0;
    __syncthreads();
    for (int e = lo + tid; e < hi; e += 256)
        atomicAdd(&hist[dst[e] >> BSH], 1);
    __syncthreads();
    for (int i = tid; i < nbuck; i += 256) {
        int c = hist[i];
        if (c) atomicAdd(&bhist[i], c);
    }
}

// ---------------------------------------------------------------------------
// scanb: single-block exclusive scan over bucket counts -> bstart, gcur.
// ---------------------------------------------------------------------------
__global__ __launch_bounds__(1024) void scanb_kernel(const int* __restrict__ bhist,
                                                     int* __restrict__ bstart,
                                                     int* __restrict__ gcur,
                                                     int* __restrict__ rstart,
                                                     int nbuck, int n_nodes) {
    __shared__ int sh[1024];
    int tid = threadIdx.x;
    int v = (tid < nbuck) ? bhist[tid] : 0;
    sh[tid] = v;
    __syncthreads();
    #pragma unroll
    for (int off = 1; off < 1024; off <<= 1) {
        int t = (tid >= off) ? sh[tid - off] : 0;
        __syncthreads();
        sh[tid] += t;
        __syncthreads();
    }
    int ex = sh[tid] - v;
    if (tid < nbuck) { bstart[tid] = ex; gcur[tid] = ex; }
    if (tid == 1023) {
        bstart[nbuck] = sh[1023];
        rstart[n_nodes] = sh[1023];   // sentinel (== n_edges)
    }
}

// ---------------------------------------------------------------------------
// bin1b: two-pass LDS-histogram binning into bucket-grouped ebuf.
// ebuf[pos] = (src << BSH) | (dst & 127)
// ---------------------------------------------------------------------------
__global__ __launch_bounds__(256) void bin1b_kernel(const int* __restrict__ src,
                                                    const int* __restrict__ dst,
                                                    int* __restrict__ gcur,
                                                    unsigned* __restrict__ ebuf,
                                                    int n_edges, int nbuck) {
    __shared__ int hist[MAXBUCK];
    __shared__ int lbase[MAXBUCK];
    const int tid = threadIdx.x;
    const int chunk = (n_edges + gridDim.x - 1) / gridDim.x;
    const int lo = blockIdx.x * chunk;
    const int hi = min(lo + chunk, n_edges);

    for (int i = tid; i < nbuck; i += 256) hist[i] = 0;
    __syncthreads();
    for (int e = lo + tid; e < hi; e += 256)
        atomicAdd(&hist[dst[e] >> BSH], 1);
    __syncthreads();
    for (int i = tid; i < nbuck; i += 256) {
        int c = hist[i];
        lbase[i] = (c > 0) ? atomicAdd(&gcur[i], c) : 0;
        hist[i] = 0;            // reuse as local cursor
    }
    __syncthreads();
    for (int e = lo + tid; e < hi; e += 256) {
        int d = dst[e];
        int bkt = d >> BSH;
        int off = atomicAdd(&hist[bkt], 1);
        ebuf[lbase[bkt] + off] = ((unsigned)src[e] << BSH) | (unsigned)(d & (BNODES - 1));
    }
}

// ---------------------------------------------------------------------------
// bin2: one block per bucket. Per-node counts from ebuf (LDS), 128-wide scan
// -> rstart + norm, then exact per-node CSR placement. All writes bucket-local.
// ---------------------------------------------------------------------------
__global__ __launch_bounds__(256) void bin2_kernel(const unsigned* __restrict__ ebuf,
                                                   const int* __restrict__ bstart,
                                                   int* __restrict__ rstart,
                                                   float* __restrict__ norm,
                                                   int* __restrict__ eidx,
                                                   int n_nodes) {
    __shared__ int lcnt[BNODES];
    __shared__ int lex[BNODES];
    const int tid = threadIdx.x;
    const int node0 = blockIdx.x << BSH;
    const int e0 = bstart[blockIdx.x];
    const int e1 = bstart[blockIdx.x + 1];

    if (tid < BNODES) lcnt[tid] = 0;
    __syncthreads();
    for (int e = e0 + tid; e < e1; e += 256)
        atomicAdd(&lcnt[ebuf[e] & (BNODES - 1)], 1);
    __syncthreads();

    int own = (tid < BNODES) ? lcnt[tid] : 0;
    if (tid < BNODES) lex[tid] = own;
    __syncthreads();
    #pragma unroll
    for (int off = 1; off < BNODES; off <<= 1) {
        int t = (tid >= off && tid < BNODES) ? lex[tid - off] : 0;
        __syncthreads();
        if (tid < BNODES) lex[tid] += t;
        __syncthreads();
    }
    if (tid < BNODES) {
        int ex = lex[tid] - own;       // exclusive
        lex[tid] = ex;
        int g = node0 + tid;
        if (g <= n_nodes) rstart[g] = e0 + ex;
        if (g < n_nodes) {
            float d = (float)own;
            if (d < 1.0f) d = 1.0f;
            norm[g] = 1.0f / sqrtf(d);
        }
        lcnt[tid] = 0;                 // reuse as cursor
    }
    __syncthreads();

    for (int e = e0 + tid; e < e1; e += 256) {
        unsigned pk = ebuf[e];
        int dl = pk & (BNODES - 1);
        int pos = atomicAdd(&lcnt[dl], 1);
        eidx[e0 + lex[dl] + pos] = (int)(pk >> BSH);
    }
}

// ---------------------------------------------------------------------------
// gemm: h = bf16( feat @ W ). ALL A-loads for the wave's 16x256 tile hoisted
// up front (16 independent float4 loads in flight -> one HBM stall instead
// of 8). B streams from L2-resident Wt behind the MFMAs.
// ---------------------------------------------------------------------------
__global__ __launch_bounds__(256) void gemm_mfma(const float* __restrict__ feat,
                                                 const unsigned short* __restrict__ Wt,
                                                 unsigned short* __restrict__ h,
                                                 int n_nodes) {
    const int wave = threadIdx.x >> 6;
    const int lane = threadIdx.x & 63;
    const int r0   = (blockIdx.x * 4 + wave) * 16;
    const int lrow = lane & 15;
    const int kgrp = (lane >> 4) * 8;

    const int row  = r0 + lrow;
    const int rowc = (row < n_nodes) ? row : (n_nodes - 1);
    const float* arow = feat + (size_t)rowc * IN_F;

    // hoist the wave's entire A footprint: 8 k-steps x 2 float4 per lane
    float4 a[16];
    #pragma unroll
    for (int k0 = 0; k0 < IN_F / 32; ++k0) {
        a[2 * k0]     = *reinterpret_cast<const float4*>(arow + k0 * 32 + kgrp);
        a[2 * k0 + 1] = *reinterpret_cast<const float4*>(arow + k0 * 32 + kgrp + 4);
    }

    f32x4 acc[8];
    #pragma unroll
    for (int n = 0; n < 8; ++n) acc[n] = (f32x4){0.f, 0.f, 0.f, 0.f};

    #pragma unroll
    for (int k0 = 0; k0 < IN_F / 32; ++k0) {
        const float4 a0 = a[2 * k0];
        const float4 a1 = a[2 * k0 + 1];
        bf16x8 afr;
        afr[0] = (short)f2bf(a0.x);
        afr[1] = (short)f2bf(a0.y);
        afr[2] = (short)f2bf(a0.z);
        afr[3] = (short)f2bf(a0.w);
        afr[4] = (short)f2bf(a1.x);
        afr[5] = (short)f2bf(a1.y);
        afr[6] = (short)f2bf(a1.z);
        afr[7] = (short)f2bf(a1.w);
        #pragma unroll
        for (int n = 0; n < 8; ++n) {
            bf16x8 bfr = *reinterpret_cast<const bf16x8*>(
                Wt + (size_t)(n * 16 + lrow) * IN_F + k0 * 32 + kgrp);
            acc[n] = __builtin_amdgcn_mfma_f32_16x16x32_bf16(afr, bfr, acc[n], 0, 0, 0);
        }
    }

    const int orow0 = r0 + (lane >> 4) * 4;
    #pragma unroll
    for (int n = 0; n < 8; ++n) {
        #pragma unroll
        for (int j = 0; j < 4; ++j) {
            int orow = orow0 + j;
            if (orow < n_nodes)
                h[(size_t)orow * OUT_F + n * 16 + lrow] = f2bf(acc[n][j]);
        }
    }
}

// ---------------------------------------------------------------------------
// agg: one wave per dst node. Per 64-edge chunk: eidx + norm[src] loaded
// lane-parallel ONCE (coalesced), distributed via shfl; h-row gathers 4-deep.
// ---------------------------------------------------------------------------
__global__ __launch_bounds__(256) void agg_kernel(const unsigned short* __restrict__ h,
                                                  const int* __restrict__ eidx,
                                                  const int* __restrict__ rstart,
                                                  const float* __restrict__ norm,
                                                  const float* __restrict__ bias,
                                                  float* __restrict__ out,
                                                  int n_nodes) {
    const int wave = threadIdx.x >> 6;
    const int lane = threadIdx.x & 63;
    const int node = blockIdx.x * 4 + wave;
    if (node >= n_nodes) return;

    const int start = rstart[node];
    const int cnt   = rstart[node + 1] - start;

    float a0 = 0.f, a1 = 0.f;
    for (int base = 0; base < cnt; base += 64) {
        const int rem = min(64, cnt - base);
        int   ev = (lane < rem) ? eidx[start + base + lane] : 0;
        float nv = (lane < rem) ? norm[ev] : 0.f;

        int j = 0;
        for (; j + 4 <= rem; j += 4) {
            int s0 = __shfl(ev, j),     s1 = __shfl(ev, j + 1);
            int s2 = __shfl(ev, j + 2), s3 = __shfl(ev, j + 3);
            float n0 = __shfl(nv, j),     n1 = __shfl(nv, j + 1);
            float n2 = __shfl(nv, j + 2), n3 = __shfl(nv, j + 3);
            unsigned v0 = *reinterpret_cast<const unsigned*>(h + (size_t)s0 * OUT_F + lane * 2);
            unsigned v1 = *reinterpret_cast<const unsigned*>(h + (size_t)s1 * OUT_F + lane * 2);
            unsigned v2 = *reinterpret_cast<const unsigned*>(h + (size_t)s2 * OUT_F + lane * 2);
            unsigned v3 = *reinterpret_cast<const unsigned*>(h + (size_t)s3 * OUT_F + lane * 2);
            a0 += bf2f((unsigned short)(v0 & 0xffffu)) * n0;
            a1 += bf2f((unsigned short)(v0 >> 16))     * n0;
            a0 += bf2f((unsigned short)(v1 & 0xffffu)) * n1;
            a1 += bf2f((unsigned short)(v1 >> 16))     * n1;
            a0 += bf2f((unsigned short)(v2 & 0xffffu)) * n2;
            a1 += bf2f((unsigned short)(v2 >> 16))     * n2;
            a0 += bf2f((unsigned short)(v3 & 0xffffu)) * n3;
            a1 += bf2f((unsigned short)(v3 >> 16))     * n3;
        }
        for (; j < rem; ++j) {
            int   s  = __shfl(ev, j);
            float nm = __shfl(nv, j);
            unsigned v = *reinterpret_cast<const unsigned*>(h + (size_t)s * OUT_F + lane * 2);
            a0 += bf2f((unsigned short)(v & 0xffffu)) * nm;
            a1 += bf2f((unsigned short)(v >> 16))     * nm;
        }
    }

    const float nd = norm[node];
    float2 r;
    r.x = a0 * nd + bias[lane * 2];
    r.y = a1 * nd + bias[lane * 2 + 1];
    *reinterpret_cast<float2*>(out + (size_t)node * OUT_F + lane * 2) = r;
}

// ---------------------------------------------------------------------------
extern "C" void kernel_launch(void* const* d_in, const int* in_sizes, int n_in,
                              void* d_out, int out_size, void* d_ws, size_t ws_size,
                              hipStream_t stream) {
    const float* feat   = (const float*)d_in[0];
    const float* weight = (const float*)d_in[1];
    const float* bias   = (const float*)d_in[2];
    const int*   src    = (const int*)d_in[3];
    const int*   dst    = (const int*)d_in[4];
    float* out = (float*)d_out;

    const int n_nodes = in_sizes[0] / IN_F;
    const int n_edges = in_sizes[3];
    const int nbuck   = (n_nodes + BNODES - 1) >> BSH;

    char* ws = (char*)d_ws;
    size_t off = 0;
    auto alloc = [&](size_t bytes) {
        char* p = ws + off;
        off += (bytes + 15) & ~(size_t)15;
        return p;
    };
    unsigned short* h  = (unsigned short*)alloc((size_t)n_nodes * OUT_F * 2);
    float* norm        = (float*)alloc((size_t)n_nodes * 4);
    int*   rstart      = (int*)alloc(((size_t)n_nodes + 1) * 4);
    int*   bhist       = (int*)alloc(MAXBUCK * 4);
    int*   bstart      = (int*)alloc((MAXBUCK + 1) * 4);
    int*   gcur        = (int*)alloc(MAXBUCK * 4);
    unsigned short* Wt = (unsigned short*)alloc((size_t)OUT_F * IN_F * 2);
    unsigned* ebuf     = (unsigned*)alloc((size_t)n_edges * 4);
    int*   eidx        = (int*)alloc((size_t)n_edges * 4);

    wprep_kernel<<<OUT_F, IN_F, 0, stream>>>(weight, Wt, bhist);
    bin1a_kernel<<<BIN_BLOCKS, 256, 0, stream>>>(dst, bhist, n_edges, nbuck);
    scanb_kernel<<<1, 1024, 0, stream>>>(bhist, bstart, gcur, rstart, nbuck, n_nodes);
    bin1b_kernel<<<BIN_BLOCKS, 256, 0, stream>>>(src, dst, gcur, ebuf, n_edges, nbuck);
    gemm_mfma<<<(n_nodes + 63) / 64, 256, 0, stream>>>(feat, Wt, h, n_nodes);
    bin2_kernel<<<nbuck, 256, 0, stream>>>(ebuf, bstart, rstart, norm, eidx, n_nodes);
    agg_kernel<<<(n_nodes + 3) / 4, 256, 0, stream>>>(h, eidx, rstart, norm, bias, out, n_nodes);
}